// Round 2
// baseline (194.809 us; speedup 1.0000x reference)
//
#include <hip/hip_runtime.h>
#include <math.h>

#define N_NODES 100000
#define N_EDGES 3200000
#define EPS_F 1e-6f

// ---- scatter: 5 slices of fp32 bins (80,000 B LDS -> 2 blocks/CU, 32 waves) ----
#define SLICE_N 20000                   // 5*20000 = 100000 == N_NODES exactly
#define NSLICE  5
#define NCHUNK  64
#define C_PAIRS (N_EDGES / 2 / NCHUNK)  // 25000 pairs per chunk (400 KB)
#define SBATCH  8

#define NVARB   6250                    // prep blocks (1 pair/thread, exact)
#define NKCLB   391                     // kcl blocks

// ws layout (4-byte words) — ~51.3 MB
//   PK_OFF   : u64 pack[N_EDGES]  lo = src | dst<<17 ; hi = (dst>>15) | cur<<2
//              prep computes cur DIRECTLY (nf is 1.6 MB -> L2-resident random reads)
//   PART_OFF : partials[NCHUNK][N_NODES]  (25.6 MB)
//   VARP_OFF : per-block float4 {s0,s1,q0,q1}[NVARB]
//   KCLP_OFF : per-block kcl partial [NKCLB]
// No gather pass: the pk round-trip (57.6 MB) and the 160 KB LDS v-table are gone.
#define PK_OFF    64
#define PART_OFF  (PK_OFF + 2 * N_EDGES)          // 6,400,064
#define VARP_OFF  (PART_OFF + NCHUNK * N_NODES)   // 12,800,064
#define KCLP_OFF  (VARP_OFF + 4 * NVARB)
#define WS_FLOATS (KCLP_OFF + NKCLB + 64)

__device__ __forceinline__ float wave_reduce(float v) {
    #pragma unroll
    for (int off = 32; off > 0; off >>= 1) v += __shfl_down(v, off, 64);
    return v;
}

__device__ __forceinline__ void fadd_agent(float* p, float v) {
    unsafeAtomicAdd(p, v);   // fallback path only
}

// bf16 pack/unpack (RNE)
__device__ __forceinline__ unsigned short f2bf(float f) {
    unsigned u = __float_as_uint(f);
    unsigned r = ((u >> 16) & 1u) + 0x7FFFu;
    return (unsigned short)((u + r) >> 16);
}
__device__ __forceinline__ float bf2f(unsigned short h) {
    return __uint_as_float(((unsigned)h) << 16);
}

// ---------------- pass 1: prep = pack ids + cur (direct nf gather) + varsum ----------------
__global__ __launch_bounds__(256) void prep_kernel(
    const float*  __restrict__ nf,
    const void*   __restrict__ eidx,
    const float*  __restrict__ logits,
    const float2* __restrict__ params,
    float*        __restrict__ ws)
{
    __shared__ float red[4][4];
    const int* i32 = (const int*)eidx;

    // int64 values < 2^31 have zero hi-words at every odd int32 slot;
    // int32 has random node ids there (16 zeros ~ impossible).
    int any = 0;
    #pragma unroll
    for (int k = 1; k < 32; k += 2) any |= i32[k];
    const bool is32 = (any != 0);

    const int t = blockIdx.x * blockDim.x + threadIdx.x;   // pair index, exact

    int2 sp, dp;
    if (is32) {
        sp = ((const int2*)i32)[t];
        dp = ((const int2*)(i32 + N_EDGES))[t];
    } else {
        const int4 a = ((const int4*)i32)[t];                  // 2x int64 src
        const int4 b = ((const int4*)(i32 + 2 * N_EDGES))[t];  // 2x int64 dst
        sp = make_int2(a.x, a.z);
        dp = make_int2(b.x, b.z);
    }

    // random 4B reads from the 1.6 MB nf table: L2-resident, hidden by 1.6M-thread TLP
    const float vs0 = nf[sp.x * 4];
    const float vd0 = nf[dp.x * 4];
    const float vs1 = nf[sp.y * 4];
    const float vd1 = nf[dp.y * 4];

    const float4 pp = ((const float4*)params)[t];
    const float2 lg = ((const float2*)logits)[t];
    const float w0 = (1.0f / (1.0f + __expf(-lg.x))) / (pp.x + pp.y + EPS_F);
    const float w1 = (1.0f / (1.0f + __expf(-lg.y))) / (pp.z + pp.w + EPS_F);
    const float c0 = fabsf(vs0 - vd0) * w0;
    const float c1 = fabsf(vs1 - vd1) * w1;

    // pack: lo = src | dst<<17 ; hi = (dst>>15) | bf16(cur)<<2
    int4 pk;
    pk.x = (int)((unsigned)sp.x | ((unsigned)dp.x << 17));
    pk.y = (int)((((unsigned)dp.x) >> 15) | ((unsigned)f2bf(c0) << 2));
    pk.z = (int)((unsigned)sp.y | ((unsigned)dp.y << 17));
    pk.w = (int)((((unsigned)dp.y) >> 15) | ((unsigned)f2bf(c1) << 2));
    ((int4*)(ws + PK_OFF))[t] = pk;

    float s0 = pp.x + pp.z;
    float s1 = pp.y + pp.w;
    float q0 = pp.x * pp.x + pp.z * pp.z;
    float q1 = pp.y * pp.y + pp.w * pp.w;

    s0 = wave_reduce(s0); s1 = wave_reduce(s1);
    q0 = wave_reduce(q0); q1 = wave_reduce(q1);

    const int wid = threadIdx.x >> 6;
    if ((threadIdx.x & 63) == 0) {
        red[wid][0] = s0; red[wid][1] = s1; red[wid][2] = q0; red[wid][3] = q1;
    }
    __syncthreads();
    if (threadIdx.x == 0) {
        float4 o;
        o.x = red[0][0] + red[1][0] + red[2][0] + red[3][0];
        o.y = red[0][1] + red[1][1] + red[2][1] + red[3][1];
        o.z = red[0][2] + red[1][2] + red[2][2] + red[3][2];
        o.w = red[0][3] + red[1][3] + red[2][3] + red[3][3];
        ((float4*)(ws + VARP_OFF))[blockIdx.x] = o;
    }
}

// ---------------- pass 2: LDS-binned scatter, 5 slices, 2 blocks/CU ----------------
// 80 KB LDS -> 2 blocks/CU (32 waves): the occupancy that sustained ~6 TB/s
// of L2 re-scan in the 8-slice config, now at half the re-read volume.
// Slice partners of chunk c: blockIdx = c + 64*s, all ≡ c (mod 8) -> same XCD;
// 8 concurrent chunks/XCD * 400 KB = 3.2 MB < 4 MB L2.
__global__ __launch_bounds__(1024) void scatter_kernel(float* __restrict__ ws)
{
    __shared__ float bins[SLICE_N];   // 80,000 B

    const int c  = blockIdx.x & (NCHUNK - 1);
    const int s  = blockIdx.x >> 6;
    const unsigned lo = (unsigned)(s * SLICE_N);

    for (int j = threadIdx.x; j < SLICE_N / 4; j += 1024)
        ((float4*)bins)[j] = make_float4(0.f, 0.f, 0.f, 0.f);
    __syncthreads();

    const int4* pk = (const int4*)(ws + PK_OFF);

    const int p0 = c * C_PAIRS;
    const int p1 = p0 + C_PAIRS;

    for (int base = p0 + (int)threadIdx.x; base < p1; base += 1024 * SBATCH) {
        int4 q[SBATCH];
        #pragma unroll
        for (int k = 0; k < SBATCH; ++k) {
            int p = base + k * 1024;
            p = (p < p1) ? p : (p1 - 1);   // clamp: loads stay unconditional
            q[k] = pk[p];
        }
        #pragma unroll
        for (int k = 0; k < SBATCH; ++k) {
            const int p = base + k * 1024;
            if (p < p1) {
                const unsigned lo0 = (unsigned)q[k].x, hi0 = (unsigned)q[k].y;
                const unsigned lo1 = (unsigned)q[k].z, hi1 = (unsigned)q[k].w;
                const unsigned s0 = (lo0 & 0x1FFFFu) - lo;
                const unsigned d0 = ((lo0 >> 17) | ((hi0 & 3u) << 15)) - lo;
                const unsigned s1 = (lo1 & 0x1FFFFu) - lo;
                const unsigned d1 = ((lo1 >> 17) | ((hi1 & 3u) << 15)) - lo;
                const float c0 = bf2f((unsigned short)((hi0 >> 2) & 0xFFFFu));
                const float c1 = bf2f((unsigned short)((hi1 >> 2) & 0xFFFFu));
                if (d0 < SLICE_N) atomicAdd(&bins[d0],  c0);
                if (s0 < SLICE_N) atomicAdd(&bins[s0], -c0);
                if (d1 < SLICE_N) atomicAdd(&bins[d1],  c1);
                if (s1 < SLICE_N) atomicAdd(&bins[s1], -c1);
            }
        }
    }
    __syncthreads();

    float4* pt4 = (float4*)(ws + PART_OFF + (size_t)c * N_NODES + lo);
    for (int j = threadIdx.x; j < SLICE_N / 4; j += 1024)
        pt4[j] = ((const float4*)bins)[j];
}

// ---------------- pass 3: merge partials, sum of squares (no atomics) ----------------
__global__ __launch_bounds__(256) void kcl_kernel(float* __restrict__ ws)
{
    __shared__ float red[4];
    const int i = blockIdx.x * blockDim.x + threadIdx.x;
    float acc = 0.f;
    if (i < N_NODES) {
        const float* p = ws + PART_OFF + i;
        float s = 0.f;
        #pragma unroll 8
        for (int c = 0; c < NCHUNK; ++c) s += p[(size_t)c * N_NODES];
        acc = s * s;
    }
    acc = wave_reduce(acc);
    if ((threadIdx.x & 63) == 0) red[threadIdx.x >> 6] = acc;
    __syncthreads();
    if (threadIdx.x == 0)
        ws[KCLP_OFF + blockIdx.x] = red[0] + red[1] + red[2] + red[3];
}

// ---------------- pass 4: final reduce of block partials ----------------
__global__ __launch_bounds__(1024) void final_kernel(
    const float* __restrict__ ws, float* __restrict__ out)
{
    __shared__ float red[16][5];
    float s0 = 0.f, s1 = 0.f, q0 = 0.f, q1 = 0.f, k = 0.f;

    const float4* vp = (const float4*)(ws + VARP_OFF);
    for (int i = threadIdx.x; i < NVARB; i += 1024) {
        const float4 v = vp[i];
        s0 += v.x; s1 += v.y; q0 += v.z; q1 += v.w;
    }
    for (int i = threadIdx.x; i < NKCLB; i += 1024) k += ws[KCLP_OFF + i];

    s0 = wave_reduce(s0); s1 = wave_reduce(s1);
    q0 = wave_reduce(q0); q1 = wave_reduce(q1);
    k  = wave_reduce(k);

    const int wid = threadIdx.x >> 6;
    if ((threadIdx.x & 63) == 0) {
        red[wid][0] = s0; red[wid][1] = s1; red[wid][2] = q0;
        red[wid][3] = q1; red[wid][4] = k;
    }
    __syncthreads();
    if (threadIdx.x == 0) {
        float a0 = 0.f, a1 = 0.f, a2 = 0.f, a3 = 0.f, a4 = 0.f;
        #pragma unroll
        for (int w = 0; w < 16; ++w) {
            a0 += red[w][0]; a1 += red[w][1]; a2 += red[w][2];
            a3 += red[w][3]; a4 += red[w][4];
        }
        const float n    = (float)N_EDGES;
        const float var0 = (a2 - a0 * a0 / n) / (n - 1.0f);
        const float var1 = (a3 - a1 * a1 / n) / (n - 1.0f);
        out[0] = a4 / (float)N_NODES + 0.5f * (var0 + var1);
    }
}

// ---------------- fallback (ws too small): agent-atomic scatter ----------------
#define FB_NODE_OFF 64
__global__ __launch_bounds__(256) void edge_kernel_fb(
    const float*  __restrict__ nf,
    const void*   __restrict__ eidx,
    const float*  __restrict__ logits,
    const float2* __restrict__ params,
    float*        __restrict__ ws)
{
    const int*       i32 = (const int*)eidx;
    const long long* i64 = (const long long*)eidx;
    int any = 0;
    #pragma unroll
    for (int k = 1; k < 32; k += 2) any |= i32[k];
    const bool is32 = (any != 0);

    float* node_sum = ws + FB_NODE_OFF;
    float* acc      = ws + 1;

    float s0 = 0.f, s1 = 0.f, q0 = 0.f, q1 = 0.f;
    const int tid    = blockIdx.x * blockDim.x + threadIdx.x;
    const int stride = gridDim.x * blockDim.x;
    for (int i = tid; i < N_EDGES; i += stride) {
        int src, dst;
        if (is32) { src = i32[i]; dst = i32[N_EDGES + i]; }
        else      { src = (int)i64[i]; dst = (int)i64[N_EDGES + i]; }
        const float2 ep = params[i];
        const float  p  = 1.0f / (1.0f + __expf(-logits[i]));
        const float cur = fabsf(nf[src * 4] - nf[dst * 4]) / (ep.x + ep.y + EPS_F) * p;
        fadd_agent(node_sum + dst,  cur);
        fadd_agent(node_sum + src, -cur);
        s0 += ep.x; s1 += ep.y; q0 += ep.x * ep.x; q1 += ep.y * ep.y;
    }
    s0 = wave_reduce(s0); s1 = wave_reduce(s1);
    q0 = wave_reduce(q0); q1 = wave_reduce(q1);
    if ((threadIdx.x & 63) == 0) {
        fadd_agent(acc + 0, s0); fadd_agent(acc + 1, s1);
        fadd_agent(acc + 2, q0); fadd_agent(acc + 3, q1);
    }
}

__global__ __launch_bounds__(256) void kcl_kernel_fb(float* __restrict__ ws)
{
    const float* node_sum = ws + FB_NODE_OFF;
    float acc = 0.f;
    const int tid    = blockIdx.x * blockDim.x + threadIdx.x;
    const int stride = gridDim.x * blockDim.x;
    for (int i = tid; i < N_NODES; i += stride) {
        const float v = node_sum[i];
        acc += v * v;
    }
    acc = wave_reduce(acc);
    if ((threadIdx.x & 63) == 0) fadd_agent(ws + 5, acc);
}

__global__ void final_kernel_fb(const float* __restrict__ ws, float* __restrict__ out)
{
    const float s0 = ws[1], s1 = ws[2], q0 = ws[3], q1 = ws[4], k = ws[5];
    const float n  = (float)N_EDGES;
    const float var0 = (q0 - s0 * s0 / n) / (n - 1.0f);
    const float var1 = (q1 - s1 * s1 / n) / (n - 1.0f);
    out[0] = k / (float)N_NODES + 0.5f * (var0 + var1);
}

extern "C" void kernel_launch(void* const* d_in, const int* in_sizes, int n_in,
                              void* d_out, int out_size, void* d_ws, size_t ws_size,
                              hipStream_t stream) {
    const float*  nf     = (const float*)d_in[0];
    const void*   eidx   = d_in[1];
    const float*  logits = (const float*)d_in[2];
    const float2* params = (const float2*)d_in[3];
    float* ws  = (float*)d_ws;
    float* out = (float*)d_out;

    const size_t need = (size_t)WS_FLOATS * sizeof(float);   // ~51.3 MB

    if (ws_size >= need) {
        prep_kernel<<<NVARB, 256, 0, stream>>>(nf, eidx, logits, params, ws);
        scatter_kernel<<<NCHUNK * NSLICE, 1024, 0, stream>>>(ws);
        kcl_kernel<<<NKCLB, 256, 0, stream>>>(ws);
        final_kernel<<<1, 1024, 0, stream>>>(ws, out);
    } else {
        hipMemsetAsync(d_ws, 0, 256 + (size_t)N_NODES * sizeof(float), stream);
        edge_kernel_fb<<<2048, 256, 0, stream>>>(nf, eidx, logits, params, ws);
        kcl_kernel_fb<<<200, 256, 0, stream>>>(ws);
        final_kernel_fb<<<1, 1, 0, stream>>>(ws, out);
    }
}

// Round 3
// 186.090 us; speedup vs baseline: 1.0469x; 1.0469x over previous
//
#include <hip/hip_runtime.h>
#include <math.h>

#define N_NODES 100000
#define N_EDGES 3200000
#define EPS_F 1e-6f

// ---- scatter: EXACT R0 geometry (proven 43 µs @ 20 B/pair), packed 16 B records ----
// grid = NCHUNK*NSLICE = 256 = #CUs (no dispatch-wave quantization), 1 block/CU,
// 800 KB chunks -> 7 batched iterations/block (ramp+tail amortized).
#define SLICE_N 12500                   // 8*12500 = 100000 == N_NODES
#define NSLICE  8
#define NCHUNK  32
#define C_PAIRS (N_EDGES / 2 / NCHUNK)  // 50000 pairs per chunk (800 KB packed)
#define SBATCH  8

#define NVARB   6250                    // prep blocks (1 pair/thread, exact)
#define NKCLB   391                     // kcl blocks (ceil(100000/256))

// ws layout (4-byte words) — ~38.5 MB (<= proven 51.3 MB budget)
//   CNT_WORD : done-counter for last-block final reduction
//   PK_OFF   : u64 pack[N_EDGES]  lo = src | dst<<17 ; hi = (dst>>15) | cur<<2
//   PART_OFF : partials[NCHUNK=32][N_NODES]  (12.8 MB)
//   VARP_OFF : per-block float4 {s0,s1,q0,q1}[NVARB]
//   KCLP_OFF : per-block kcl partial [NKCLB]
#define CNT_WORD  32
#define PK_OFF    64
#define PART_OFF  (PK_OFF + 2 * N_EDGES)          // 6,400,064
#define VARP_OFF  (PART_OFF + NCHUNK * N_NODES)   // 9,600,064
#define KCLP_OFF  (VARP_OFF + 4 * NVARB)
#define WS_FLOATS (KCLP_OFF + NKCLB + 64)

__device__ __forceinline__ float wave_reduce(float v) {
    #pragma unroll
    for (int off = 32; off > 0; off >>= 1) v += __shfl_down(v, off, 64);
    return v;
}

__device__ __forceinline__ void fadd_agent(float* p, float v) {
    unsafeAtomicAdd(p, v);   // fallback path only
}

// bf16 pack/unpack (RNE)
__device__ __forceinline__ unsigned short f2bf(float f) {
    unsigned u = __float_as_uint(f);
    unsigned r = ((u >> 16) & 1u) + 0x7FFFu;
    return (unsigned short)((u + r) >> 16);
}
__device__ __forceinline__ float bf2f(unsigned short h) {
    return __uint_as_float(((unsigned)h) << 16);
}

// ---------------- pass 1: prep = pack ids + cur (direct nf gather) + varsum ----------------
__global__ __launch_bounds__(256) void prep_kernel(
    const float*  __restrict__ nf,
    const void*   __restrict__ eidx,
    const float*  __restrict__ logits,
    const float2* __restrict__ params,
    float*        __restrict__ ws)
{
    __shared__ float red[4][4];
    const int* i32 = (const int*)eidx;

    // int64 values < 2^31 have zero hi-words at every odd int32 slot;
    // int32 has random node ids there (16 zeros ~ impossible).
    int any = 0;
    #pragma unroll
    for (int k = 1; k < 32; k += 2) any |= i32[k];
    const bool is32 = (any != 0);

    const int t = blockIdx.x * blockDim.x + threadIdx.x;   // pair index, exact

    if (t == 0) ((unsigned*)ws)[CNT_WORD] = 0;             // reset done-counter

    int2 sp, dp;
    if (is32) {
        sp = ((const int2*)i32)[t];
        dp = ((const int2*)(i32 + N_EDGES))[t];
    } else {
        const int4 a = ((const int4*)i32)[t];                  // 2x int64 src
        const int4 b = ((const int4*)(i32 + 2 * N_EDGES))[t];  // 2x int64 dst
        sp = make_int2(a.x, a.z);
        dp = make_int2(b.x, b.z);
    }

    // random 4B reads from the 1.6 MB nf table: L2-resident, hidden by 1.6M-thread TLP
    const float vs0 = nf[sp.x * 4];
    const float vd0 = nf[dp.x * 4];
    const float vs1 = nf[sp.y * 4];
    const float vd1 = nf[dp.y * 4];

    const float4 pp = ((const float4*)params)[t];
    const float2 lg = ((const float2*)logits)[t];
    const float w0 = (1.0f / (1.0f + __expf(-lg.x))) / (pp.x + pp.y + EPS_F);
    const float w1 = (1.0f / (1.0f + __expf(-lg.y))) / (pp.z + pp.w + EPS_F);
    const float c0 = fabsf(vs0 - vd0) * w0;
    const float c1 = fabsf(vs1 - vd1) * w1;

    // pack: lo = src | dst<<17 ; hi = (dst>>15) | bf16(cur)<<2
    int4 pk;
    pk.x = (int)((unsigned)sp.x | ((unsigned)dp.x << 17));
    pk.y = (int)((((unsigned)dp.x) >> 15) | ((unsigned)f2bf(c0) << 2));
    pk.z = (int)((unsigned)sp.y | ((unsigned)dp.y << 17));
    pk.w = (int)((((unsigned)dp.y) >> 15) | ((unsigned)f2bf(c1) << 2));
    ((int4*)(ws + PK_OFF))[t] = pk;

    float s0 = pp.x + pp.z;
    float s1 = pp.y + pp.w;
    float q0 = pp.x * pp.x + pp.z * pp.z;
    float q1 = pp.y * pp.y + pp.w * pp.w;

    s0 = wave_reduce(s0); s1 = wave_reduce(s1);
    q0 = wave_reduce(q0); q1 = wave_reduce(q1);

    const int wid = threadIdx.x >> 6;
    if ((threadIdx.x & 63) == 0) {
        red[wid][0] = s0; red[wid][1] = s1; red[wid][2] = q0; red[wid][3] = q1;
    }
    __syncthreads();
    if (threadIdx.x == 0) {
        float4 o;
        o.x = red[0][0] + red[1][0] + red[2][0] + red[3][0];
        o.y = red[0][1] + red[1][1] + red[2][1] + red[3][1];
        o.z = red[0][2] + red[1][2] + red[2][2] + red[3][2];
        o.w = red[0][3] + red[1][3] + red[2][3] + red[3][3];
        ((float4*)(ws + VARP_OFF))[blockIdx.x] = o;
    }
}

// ---------------- pass 2: LDS-binned scatter — R0 schedule, packed records ----------------
// grid 256 (1 block/CU, no second dispatch wave), 50K pairs/chunk -> 7 iterations,
// SBATCH=8 int4 loads (128 B in flight/thread). Slice partners of chunk c are
// blockIdx = c + 32*s ≡ c (mod 8) -> same XCD; 4 chunks/XCD * 800 KB = 3.2 MB < 4 MB L2.
__global__ __launch_bounds__(1024) void scatter_kernel(float* __restrict__ ws)
{
    __shared__ float bins[SLICE_N];   // 50,000 B

    const int c  = blockIdx.x & (NCHUNK - 1);
    const int s  = blockIdx.x >> 5;
    const unsigned lo = (unsigned)(s * SLICE_N);

    for (int j = threadIdx.x; j < SLICE_N; j += 1024) bins[j] = 0.f;
    __syncthreads();

    const int4* pk = (const int4*)(ws + PK_OFF);

    const int p0 = c * C_PAIRS;
    const int p1 = p0 + C_PAIRS;

    for (int base = p0 + (int)threadIdx.x; base < p1; base += 1024 * SBATCH) {
        int4 q[SBATCH];
        #pragma unroll
        for (int k = 0; k < SBATCH; ++k) {
            int p = base + k * 1024;
            p = (p < p1) ? p : (p1 - 1);   // clamp: loads stay unconditional
            q[k] = pk[p];
        }
        #pragma unroll
        for (int k = 0; k < SBATCH; ++k) {
            const int p = base + k * 1024;
            if (p < p1) {
                const unsigned lo0 = (unsigned)q[k].x, hi0 = (unsigned)q[k].y;
                const unsigned lo1 = (unsigned)q[k].z, hi1 = (unsigned)q[k].w;
                const unsigned s0 = (lo0 & 0x1FFFFu) - lo;
                const unsigned d0 = ((lo0 >> 17) | ((hi0 & 3u) << 15)) - lo;
                const unsigned s1 = (lo1 & 0x1FFFFu) - lo;
                const unsigned d1 = ((lo1 >> 17) | ((hi1 & 3u) << 15)) - lo;
                const float c0 = bf2f((unsigned short)((hi0 >> 2) & 0xFFFFu));
                const float c1 = bf2f((unsigned short)((hi1 >> 2) & 0xFFFFu));
                if (d0 < SLICE_N) atomicAdd(&bins[d0],  c0);
                if (s0 < SLICE_N) atomicAdd(&bins[s0], -c0);
                if (d1 < SLICE_N) atomicAdd(&bins[d1],  c1);
                if (s1 < SLICE_N) atomicAdd(&bins[s1], -c1);
            }
        }
    }
    __syncthreads();

    float4* pt4 = (float4*)(ws + PART_OFF + (size_t)c * N_NODES + lo);
    for (int j = threadIdx.x; j < SLICE_N / 4; j += 1024)
        pt4[j] = ((const float4*)bins)[j];
}

// ---------------- pass 3: merge partials + squares; LAST block folds final ----------------
__global__ __launch_bounds__(256) void kclfinal_kernel(float* __restrict__ ws,
                                                       float* __restrict__ out)
{
    __shared__ float red[4];
    __shared__ unsigned last;

    const int i = blockIdx.x * blockDim.x + threadIdx.x;
    float acc = 0.f;
    if (i < N_NODES) {
        const float* p = ws + PART_OFF + i;
        float s = 0.f;
        #pragma unroll 8
        for (int c = 0; c < NCHUNK; ++c) s += p[(size_t)c * N_NODES];
        acc = s * s;
    }
    acc = wave_reduce(acc);
    if ((threadIdx.x & 63) == 0) red[threadIdx.x >> 6] = acc;
    __syncthreads();
    if (threadIdx.x == 0) {
        ws[KCLP_OFF + blockIdx.x] = red[0] + red[1] + red[2] + red[3];
        __threadfence();   // KCLP store visible before counter bump
        const unsigned old = atomicAdd((unsigned*)ws + CNT_WORD, 1u);
        last = (old == NKCLB - 1) ? 1u : 0u;
    }
    __syncthreads();
    if (!last) return;

    // ---- final reduction (one block, 256 threads) ----
    __shared__ float red2[4][5];
    float s0 = 0.f, s1 = 0.f, q0 = 0.f, q1 = 0.f, k = 0.f;

    const float4* vp = (const float4*)(ws + VARP_OFF);   // prep output: kernel-boundary safe
    for (int j = threadIdx.x; j < NVARB; j += 256) {
        const float4 v = vp[j];
        s0 += v.x; s1 += v.y; q0 += v.z; q1 += v.w;
    }
    // KCLP written by other blocks this kernel: cross-XCD L2 not coherent ->
    // read via device-scope atomic RMW (+0.0 returns old value).
    for (int j = threadIdx.x; j < NKCLB; j += 256)
        k += unsafeAtomicAdd(ws + KCLP_OFF + j, 0.0f);

    s0 = wave_reduce(s0); s1 = wave_reduce(s1);
    q0 = wave_reduce(q0); q1 = wave_reduce(q1);
    k  = wave_reduce(k);

    const int wid = threadIdx.x >> 6;
    if ((threadIdx.x & 63) == 0) {
        red2[wid][0] = s0; red2[wid][1] = s1; red2[wid][2] = q0;
        red2[wid][3] = q1; red2[wid][4] = k;
    }
    __syncthreads();
    if (threadIdx.x == 0) {
        float a0 = 0.f, a1 = 0.f, a2 = 0.f, a3 = 0.f, a4 = 0.f;
        #pragma unroll
        for (int w = 0; w < 4; ++w) {
            a0 += red2[w][0]; a1 += red2[w][1]; a2 += red2[w][2];
            a3 += red2[w][3]; a4 += red2[w][4];
        }
        const float n    = (float)N_EDGES;
        const float var0 = (a2 - a0 * a0 / n) / (n - 1.0f);
        const float var1 = (a3 - a1 * a1 / n) / (n - 1.0f);
        out[0] = a4 / (float)N_NODES + 0.5f * (var0 + var1);
    }
}

// ---------------- fallback (ws too small): agent-atomic scatter ----------------
#define FB_NODE_OFF 64
__global__ __launch_bounds__(256) void edge_kernel_fb(
    const float*  __restrict__ nf,
    const void*   __restrict__ eidx,
    const float*  __restrict__ logits,
    const float2* __restrict__ params,
    float*        __restrict__ ws)
{
    const int*       i32 = (const int*)eidx;
    const long long* i64 = (const long long*)eidx;
    int any = 0;
    #pragma unroll
    for (int k = 1; k < 32; k += 2) any |= i32[k];
    const bool is32 = (any != 0);

    float* node_sum = ws + FB_NODE_OFF;
    float* acc      = ws + 1;

    float s0 = 0.f, s1 = 0.f, q0 = 0.f, q1 = 0.f;
    const int tid    = blockIdx.x * blockDim.x + threadIdx.x;
    const int stride = gridDim.x * blockDim.x;
    for (int i = tid; i < N_EDGES; i += stride) {
        int src, dst;
        if (is32) { src = i32[i]; dst = i32[N_EDGES + i]; }
        else      { src = (int)i64[i]; dst = (int)i64[N_EDGES + i]; }
        const float2 ep = params[i];
        const float  p  = 1.0f / (1.0f + __expf(-logits[i]));
        const float cur = fabsf(nf[src * 4] - nf[dst * 4]) / (ep.x + ep.y + EPS_F) * p;
        fadd_agent(node_sum + dst,  cur);
        fadd_agent(node_sum + src, -cur);
        s0 += ep.x; s1 += ep.y; q0 += ep.x * ep.x; q1 += ep.y * ep.y;
    }
    s0 = wave_reduce(s0); s1 = wave_reduce(s1);
    q0 = wave_reduce(q0); q1 = wave_reduce(q1);
    if ((threadIdx.x & 63) == 0) {
        fadd_agent(acc + 0, s0); fadd_agent(acc + 1, s1);
        fadd_agent(acc + 2, q0); fadd_agent(acc + 3, q1);
    }
}

__global__ __launch_bounds__(256) void kcl_kernel_fb(float* __restrict__ ws)
{
    const float* node_sum = ws + FB_NODE_OFF;
    float acc = 0.f;
    const int tid    = blockIdx.x * blockDim.x + threadIdx.x;
    const int stride = gridDim.x * blockDim.x;
    for (int i = tid; i < N_NODES; i += stride) {
        const float v = node_sum[i];
        acc += v * v;
    }
    acc = wave_reduce(acc);
    if ((threadIdx.x & 63) == 0) fadd_agent(ws + 5, acc);
}

__global__ void final_kernel_fb(const float* __restrict__ ws, float* __restrict__ out)
{
    const float s0 = ws[1], s1 = ws[2], q0 = ws[3], q1 = ws[4], k = ws[5];
    const float n  = (float)N_EDGES;
    const float var0 = (q0 - s0 * s0 / n) / (n - 1.0f);
    const float var1 = (q1 - s1 * s1 / n) / (n - 1.0f);
    out[0] = k / (float)N_NODES + 0.5f * (var0 + var1);
}

extern "C" void kernel_launch(void* const* d_in, const int* in_sizes, int n_in,
                              void* d_out, int out_size, void* d_ws, size_t ws_size,
                              hipStream_t stream) {
    const float*  nf     = (const float*)d_in[0];
    const void*   eidx   = d_in[1];
    const float*  logits = (const float*)d_in[2];
    const float2* params = (const float2*)d_in[3];
    float* ws  = (float*)d_ws;
    float* out = (float*)d_out;

    const size_t need = (size_t)WS_FLOATS * sizeof(float);   // ~38.5 MB

    if (ws_size >= need) {
        prep_kernel<<<NVARB, 256, 0, stream>>>(nf, eidx, logits, params, ws);
        scatter_kernel<<<NCHUNK * NSLICE, 1024, 0, stream>>>(ws);
        kclfinal_kernel<<<NKCLB, 256, 0, stream>>>(ws, out);
    } else {
        hipMemsetAsync(d_ws, 0, 256 + (size_t)N_NODES * sizeof(float), stream);
        edge_kernel_fb<<<2048, 256, 0, stream>>>(nf, eidx, logits, params, ws);
        kcl_kernel_fb<<<200, 256, 0, stream>>>(ws);
        final_kernel_fb<<<1, 1, 0, stream>>>(ws, out);
    }
}